// Round 3
// baseline (424.051 us; speedup 1.0000x reference)
//
#include <hip/hip_runtime.h>

#define NCTX 4096
#define DMODEL 2048
#define DHEAD 128

typedef short s16x8 __attribute__((ext_vector_type(8)));
typedef float f32x4 __attribute__((ext_vector_type(4)));
typedef unsigned short u16;

__device__ __forceinline__ u16 f2bf(float f) {
  union { float f; unsigned u; } v; v.f = f;
  unsigned u = v.u;
  return (u16)((u + 0x7FFFu + ((u >> 16) & 1u)) >> 16);
}
__device__ __forceinline__ float bf2f(u16 h) {
  union { unsigned u; float f; } v; v.u = ((unsigned)h) << 16; return v.f;
}

__device__ __forceinline__ void gl_lds16(const void* g, void* l) {
  __builtin_amdgcn_global_load_lds((const __attribute__((address_space(1))) void*)g,
                                   (__attribute__((address_space(3))) void*)l, 16, 0, 0);
}

// ---------------- elementwise fp32 -> bf16 cast ----------------
__global__ __launch_bounds__(256) void cast_f32_bf16(const float* __restrict__ in,
                                                     u16* __restrict__ out, int n4) {
  int i = blockIdx.x * 256 + threadIdx.x;
  if (i >= n4) return;
  float4 v = ((const float4*)in)[i];
  ushort4 o;
  o.x = f2bf(v.x); o.y = f2bf(v.y); o.z = f2bf(v.z); o.w = f2bf(v.w);
  ((ushort4*)out)[i] = o;
}

// ---------------- fp32 -> (hi, lo) bf16 split ----------------
__global__ __launch_bounds__(256) void split_f32_bf16x2(const float* __restrict__ in,
                                                        u16* __restrict__ hi,
                                                        u16* __restrict__ lo, int n4) {
  int i = blockIdx.x * 256 + threadIdx.x;
  if (i >= n4) return;
  float4 v = ((const float4*)in)[i];
  ushort4 h, l;
  h.x = f2bf(v.x); l.x = f2bf(v.x - bf2f(h.x));
  h.y = f2bf(v.y); l.y = f2bf(v.y - bf2f(h.y));
  h.z = f2bf(v.z); l.z = f2bf(v.z - bf2f(h.z));
  h.w = f2bf(v.w); l.w = f2bf(v.w - bf2f(h.w));
  ((ushort4*)hi)[i] = h;
  ((ushort4*)lo)[i] = l;
}

// ---------------- x [4096,2048] fp32 -> xT [2048,4096] bf16 ----------------
__global__ __launch_bounds__(256) void transpose_cast(const float* __restrict__ X,
                                                      u16* __restrict__ XT) {
  __shared__ float tile[64][65];
  int db = blockIdx.x * 64, mb = blockIdx.y * 64;
  int tx = threadIdx.x & 63, ty = threadIdx.x >> 6;
#pragma unroll
  for (int r = 0; r < 16; ++r) {
    int row = ty * 16 + r;
    tile[row][tx] = X[(size_t)(mb + row) * DMODEL + db + tx];
  }
  __syncthreads();
#pragma unroll
  for (int r = 0; r < 16; ++r) {
    int row = ty * 16 + r;
    XT[(size_t)(db + row) * NCTX + mb + tx] = f2bf(tile[tx][row]);
  }
}

// ---------------- row softmax (fp32) -> bf16 attn ----------------
// zero-fills only up to the 128-aligned diagonal band end (gemm reads no further).
__global__ __launch_bounds__(256) void softmax_rows(const float* __restrict__ S,
                                                    u16* __restrict__ P) {
  int i = blockIdx.x;
  int t = threadIdx.x;
  __shared__ float rowbuf[NCTX];
  __shared__ float red[4];
  __shared__ float red2[4];
  const float* srow = S + (size_t)i * NCTX;
  int len = i + 1;
  int jmax = ((i >> 7) + 1) << 7;  // causal gemm reads j < 128*(bm+1)
  float mx = -3.0e38f;
  for (int j = t; j < len; j += 256) {
    float v = srow[j];
    rowbuf[j] = v;
    mx = fmaxf(mx, v);
  }
#pragma unroll
  for (int o = 32; o > 0; o >>= 1) mx = fmaxf(mx, __shfl_xor(mx, o, 64));
  if ((t & 63) == 0) red[t >> 6] = mx;
  __syncthreads();
  mx = fmaxf(fmaxf(red[0], red[1]), fmaxf(red[2], red[3]));
  float sum = 0.f;
  for (int j = t; j < len; j += 256) sum += __expf(rowbuf[j] - mx);
#pragma unroll
  for (int o = 32; o > 0; o >>= 1) sum += __shfl_xor(sum, o, 64);
  if ((t & 63) == 0) red2[t >> 6] = sum;
  __syncthreads();
  float inv = 1.0f / (red2[0] + red2[1] + red2[2] + red2[3]);
  u16* prow = P + (size_t)i * NCTX;
  for (int j = t; j < jmax; j += 256) {
    float v = (j < len) ? __expf(rowbuf[j] - mx) * inv : 0.0f;
    prow[j] = f2bf(v);
  }
}

// ---------------- bf16 MFMA GEMM, B^T layout, split-K + atomic epilogue ----------
// C[M,N] fp32 (pre-zeroed) += A[M,K] (bf16 rm) * B[N,K]^T (bf16 rm).
// 128x128 tile, BK=32; grid (M/128, N/128, ceil(K/KC)).
// causal: K-range additionally clipped to (bm+1)*128.
__global__ __launch_bounds__(256) void gemm_bt_sk(const u16* __restrict__ A,
                                                  const u16* __restrict__ B,
                                                  float* __restrict__ C,
                                                  int M, int N, int K, int KC, int causal) {
  int bm = blockIdx.x, bn = blockIdx.y, kc = blockIdx.z;
  int kEnd = K;
  if (causal) { int ke = (bm + 1) * 128; if (ke < kEnd) kEnd = ke; }
  int kStart = kc * KC;
  if (kStart >= kEnd) return;
  int kStop = kStart + KC < kEnd ? kStart + KC : kEnd;
  __shared__ __align__(16) u16 As[128 * 32];
  __shared__ __align__(16) u16 Bs[128 * 32];
  int t = threadIdx.x;
  int lane = t & 63, w = t >> 6;
  int m0 = bm * 128, n0 = bn * 128;
  int wm = (w >> 1) * 64, wn = (w & 1) * 64;
  int mfrag = lane & 15, quad = lane >> 4;
  int srow = t >> 2, schunk = t & 3;
  f32x4 acc[4][4] = {};
  for (int kt = kStart; kt < kStop; kt += 32) {
#pragma unroll
    for (int p = 0; p < 2; ++p) {
      int row = p * 64 + srow;
      gl_lds16(A + (size_t)(m0 + row) * K + kt + schunk * 8, As + (size_t)(p * 256 + t) * 8);
      gl_lds16(B + (size_t)(n0 + row) * K + kt + schunk * 8, Bs + (size_t)(p * 256 + t) * 8);
    }
    __syncthreads();
    s16x8 af[4], bfr[4];
#pragma unroll
    for (int i = 0; i < 4; ++i)
      af[i] = *(const s16x8*)(As + (wm + i * 16 + mfrag) * 32 + quad * 8);
#pragma unroll
    for (int j = 0; j < 4; ++j)
      bfr[j] = *(const s16x8*)(Bs + (wn + j * 16 + mfrag) * 32 + quad * 8);
#pragma unroll
    for (int i = 0; i < 4; ++i)
#pragma unroll
      for (int j = 0; j < 4; ++j)
        acc[i][j] = __builtin_amdgcn_mfma_f32_16x16x32_bf16(af[i], bfr[j], acc[i][j], 0, 0, 0);
    __syncthreads();
  }
#pragma unroll
  for (int i = 0; i < 4; ++i)
#pragma unroll
    for (int j = 0; j < 4; ++j)
#pragma unroll
      for (int rr = 0; rr < 4; ++rr) {
        int row = m0 + wm + i * 16 + quad * 4 + rr;
        int col = n0 + wn + j * 16 + mfrag;
        atomicAdd(&C[(size_t)row * N + col], acc[i][j][rr]);
      }
}

// ---------------- bf16x3 split-precision MFMA GEMM, B^T, split-K + atomics -------
// C (pre-zeroed) += (Ah+Al) @ (Bh+Bl)^T ~= Ah@Bh + Al@Bh + Ah@Bl  (fp32-accurate)
// grid (M/128, N/128, ceil(K/KC)); causal: skip bn > bm tiles.
__global__ __launch_bounds__(256) void gemm_bt3_sk(const u16* __restrict__ Ah,
                                                   const u16* __restrict__ Al,
                                                   const u16* __restrict__ Bh,
                                                   const u16* __restrict__ Bl,
                                                   float* __restrict__ C,
                                                   int lda, int ldb, int ldc,
                                                   int K, int KC, int causal) {
  int bm = blockIdx.x, bn = blockIdx.y, kc = blockIdx.z;
  if (causal && bn > bm) return;
  int kStart = kc * KC;
  if (kStart >= K) return;
  int kStop = kStart + KC < K ? kStart + KC : K;
  __shared__ __align__(16) u16 Ash[128 * 32];
  __shared__ __align__(16) u16 Asl[128 * 32];
  __shared__ __align__(16) u16 Bsh[128 * 32];
  __shared__ __align__(16) u16 Bsl[128 * 32];
  int t = threadIdx.x;
  int lane = t & 63, w = t >> 6;
  int m0 = bm * 128, n0 = bn * 128;
  int wm = (w >> 1) * 64, wn = (w & 1) * 64;
  int mfrag = lane & 15, quad = lane >> 4;
  int srow = t >> 2, schunk = t & 3;
  f32x4 acc[4][4] = {};
  for (int kt = kStart; kt < kStop; kt += 32) {
#pragma unroll
    for (int p = 0; p < 2; ++p) {
      int row = p * 64 + srow;
      size_t aoff = (size_t)(m0 + row) * lda + kt + schunk * 8;
      size_t boff = (size_t)(n0 + row) * ldb + kt + schunk * 8;
      size_t loff = (size_t)(p * 256 + t) * 8;
      gl_lds16(Ah + aoff, Ash + loff);
      gl_lds16(Al + aoff, Asl + loff);
      gl_lds16(Bh + boff, Bsh + loff);
      gl_lds16(Bl + boff, Bsl + loff);
    }
    __syncthreads();
    s16x8 a0[4], a1[4], b0[4];
#pragma unroll
    for (int i = 0; i < 4; ++i)
      a0[i] = *(const s16x8*)(Ash + (wm + i * 16 + mfrag) * 32 + quad * 8);
#pragma unroll
    for (int j = 0; j < 4; ++j)
      b0[j] = *(const s16x8*)(Bsh + (wn + j * 16 + mfrag) * 32 + quad * 8);
#pragma unroll
    for (int i = 0; i < 4; ++i)
#pragma unroll
      for (int j = 0; j < 4; ++j)
        acc[i][j] = __builtin_amdgcn_mfma_f32_16x16x32_bf16(a0[i], b0[j], acc[i][j], 0, 0, 0);
#pragma unroll
    for (int i = 0; i < 4; ++i)
      a1[i] = *(const s16x8*)(Asl + (wm + i * 16 + mfrag) * 32 + quad * 8);
#pragma unroll
    for (int i = 0; i < 4; ++i)
#pragma unroll
      for (int j = 0; j < 4; ++j)
        acc[i][j] = __builtin_amdgcn_mfma_f32_16x16x32_bf16(a1[i], b0[j], acc[i][j], 0, 0, 0);
#pragma unroll
    for (int j = 0; j < 4; ++j)
      b0[j] = *(const s16x8*)(Bsl + (wn + j * 16 + mfrag) * 32 + quad * 8);
#pragma unroll
    for (int i = 0; i < 4; ++i)
#pragma unroll
      for (int j = 0; j < 4; ++j)
        acc[i][j] = __builtin_amdgcn_mfma_f32_16x16x32_bf16(a0[i], b0[j], acc[i][j], 0, 0, 0);
    __syncthreads();
  }
  if (gridDim.z == 1) {
#pragma unroll
    for (int i = 0; i < 4; ++i)
#pragma unroll
      for (int j = 0; j < 4; ++j)
#pragma unroll
        for (int rr = 0; rr < 4; ++rr) {
          int row = m0 + wm + i * 16 + quad * 4 + rr;
          int col = n0 + wn + j * 16 + mfrag;
          C[(size_t)row * ldc + col] = acc[i][j][rr];
        }
  } else {
#pragma unroll
    for (int i = 0; i < 4; ++i)
#pragma unroll
      for (int j = 0; j < 4; ++j)
#pragma unroll
        for (int rr = 0; rr < 4; ++rr) {
          int row = m0 + wm + i * 16 + quad * 4 + rr;
          int col = n0 + wn + j * 16 + mfrag;
          atomicAdd(&C[(size_t)row * ldc + col], acc[i][j][rr]);
        }
  }
}

extern "C" void kernel_launch(void* const* d_in, const int* in_sizes, int n_in,
                              void* d_out, int out_size, void* d_ws, size_t ws_size,
                              hipStream_t stream) {
  const float* x  = (const float*)d_in[0];
  const float* Wk = (const float*)d_in[1];
  const float* Wq = (const float*)d_in[2];
  const float* W2 = (const float*)d_in[3];

  char* ws = (char*)d_ws;
  const size_t MB = 1024 * 1024;
  float* QK   = (float*)(ws + 0);            //  4 MB  [4096,256] fp32 (q | k)
  u16*   QKh  = (u16*)  (ws + 4 * MB);       //  2 MB
  u16*   QKl  = (u16*)  (ws + 6 * MB);       //  2 MB
  u16*   Wh   = (u16*)  (ws + 8 * MB);       //  1 MB  [256,2048] (Wq ; Wk) hi
  u16*   Wl   = (u16*)  (ws + 9 * MB);       //  1 MB  lo
  u16*   xT   = (u16*)  (ws + 10 * MB);      // 16 MB  [2048,4096] bf16
  u16*   W2b  = (u16*)  (ws + 26 * MB);      //  8 MB  [2048,2048] bf16
  u16*   outb = (u16*)  (ws + 34 * MB);      // 16 MB  [4096,2048] bf16
  u16*   attn = (u16*)  (ws + 50 * MB);      // 32 MB  [4096,4096] bf16
  u16*   xh   = (u16*)  (ws + 82 * MB);      // 16 MB  (dead after qk gemm)
  u16*   xl   = (u16*)  (ws + 98 * MB);      // 16 MB  (dead after qk gemm)
  float* S    = (float*)(ws + 82 * MB);      // 64 MB  ALIASES xh/xl (written after dead)
  float* outf = S;                           // 32 MB alias (S dead after softmax)

  const int XN4 = NCTX * DMODEL / 4;
  const int WN4 = DHEAD * DMODEL / 4;
  const int QKN4 = NCTX * 256 / 4;

  // precision-critical path: bf16x3 splits
  split_f32_bf16x2<<<(XN4 + 255) / 256, 256, 0, stream>>>(x, xh, xl, XN4);
  split_f32_bf16x2<<<(WN4 + 255) / 256, 256, 0, stream>>>(Wq, Wh, Wl, WN4);
  split_f32_bf16x2<<<(WN4 + 255) / 256, 256, 0, stream>>>(Wk, Wh + (size_t)DHEAD * DMODEL,
                                                          Wl + (size_t)DHEAD * DMODEL, WN4);
  cast_f32_bf16<<<(2048 * 2048 / 4 + 255) / 256, 256, 0, stream>>>(W2, W2b, 2048 * 2048 / 4);
  transpose_cast<<<dim3(DMODEL / 64, NCTX / 64), 256, 0, stream>>>(x, xT);

  // q,k = x @ [Wq;Wk]^T  via bf16x3, split-K (KC=256 -> 512 blocks)
  hipMemsetAsync(QK, 0, (size_t)NCTX * 256 * 4, stream);
  gemm_bt3_sk<<<dim3(NCTX / 128, 2, DMODEL / 256), 256, 0, stream>>>(
      xh, xl, Wh, Wl, QK, DMODEL, DMODEL, 256, DMODEL, 256, 0);
  split_f32_bf16x2<<<(QKN4 + 255) / 256, 256, 0, stream>>>(QK, QKh, QKl, QKN4);

  // scores = q @ k^T (causal tiles), K=128: no split needed
  gemm_bt3_sk<<<dim3(NCTX / 128, NCTX / 128, 1), 256, 0, stream>>>(
      QKh, QKl, QKh + DHEAD, QKl + DHEAD, S, 256, 256, NCTX, DHEAD, DHEAD, 1);
  softmax_rows<<<NCTX, 256, 0, stream>>>(S, attn);

  // out = attn @ x (causal), split-K KC=1024 -> 1280 active blocks
  hipMemsetAsync(outf, 0, (size_t)NCTX * DMODEL * 4, stream);
  gemm_bt_sk<<<dim3(NCTX / 128, DMODEL / 128, NCTX / 1024), 256, 0, stream>>>(
      attn, xT, outf, NCTX, DMODEL, NCTX, 1024, 1);
  cast_f32_bf16<<<(XN4 + 255) / 256, 256, 0, stream>>>(outf, outb, XN4);

  // final = out @ W2^T, split-K KC=1024 -> 1024 blocks
  hipMemsetAsync(d_out, 0, (size_t)NCTX * DMODEL * 4, stream);
  gemm_bt_sk<<<dim3(NCTX / 128, DMODEL / 128, DMODEL / 1024), 256, 0, stream>>>(
      outb, W2b, (float*)d_out, NCTX, DMODEL, DMODEL, 1024, 0);
}

// Round 4
// 364.659 us; speedup vs baseline: 1.1629x; 1.1629x over previous
//
#include <hip/hip_runtime.h>

#define NCTX 4096
#define DMODEL 2048
#define DHEAD 128

typedef short s16x8 __attribute__((ext_vector_type(8)));
typedef float f32x4 __attribute__((ext_vector_type(4)));
typedef unsigned short u16;

__device__ __forceinline__ u16 f2bf(float f) {
  union { float f; unsigned u; } v; v.f = f;
  unsigned u = v.u;
  return (u16)((u + 0x7FFFu + ((u >> 16) & 1u)) >> 16);
}
__device__ __forceinline__ float bf2f(u16 h) {
  union { unsigned u; float f; } v; v.u = ((unsigned)h) << 16; return v.f;
}

__device__ __forceinline__ void gl_lds16(const void* g, void* l) {
  __builtin_amdgcn_global_load_lds((const __attribute__((address_space(1))) void*)g,
                                   (__attribute__((address_space(3))) void*)l, 16, 0, 0);
}

// ---------------- elementwise fp32 -> bf16 cast ----------------
__global__ __launch_bounds__(256) void cast_f32_bf16(const float* __restrict__ in,
                                                     u16* __restrict__ out, int n4) {
  int i = blockIdx.x * 256 + threadIdx.x;
  if (i >= n4) return;
  float4 v = ((const float4*)in)[i];
  ushort4 o;
  o.x = f2bf(v.x); o.y = f2bf(v.y); o.z = f2bf(v.z); o.w = f2bf(v.w);
  ((ushort4*)out)[i] = o;
}

// ---------------- fp32 -> (hi, lo) bf16 split ----------------
__global__ __launch_bounds__(256) void split_f32_bf16x2(const float* __restrict__ in,
                                                        u16* __restrict__ hi,
                                                        u16* __restrict__ lo, int n4) {
  int i = blockIdx.x * 256 + threadIdx.x;
  if (i >= n4) return;
  float4 v = ((const float4*)in)[i];
  ushort4 h, l;
  h.x = f2bf(v.x); l.x = f2bf(v.x - bf2f(h.x));
  h.y = f2bf(v.y); l.y = f2bf(v.y - bf2f(h.y));
  h.z = f2bf(v.z); l.z = f2bf(v.z - bf2f(h.z));
  h.w = f2bf(v.w); l.w = f2bf(v.w - bf2f(h.w));
  ((ushort4*)hi)[i] = h;
  ((ushort4*)lo)[i] = l;
}

// ---------------- 8-way split-K reduce -> (hi, lo) bf16 split ----------------
__global__ __launch_bounds__(256) void reduce8_split(const float* __restrict__ P,
                                                     u16* __restrict__ hi,
                                                     u16* __restrict__ lo, int n4) {
  int i = blockIdx.x * 256 + threadIdx.x;
  if (i >= n4) return;
  float4 s = ((const float4*)P)[i];
#pragma unroll
  for (int z = 1; z < 8; ++z) {
    float4 v = ((const float4*)P)[(size_t)z * n4 + i];
    s.x += v.x; s.y += v.y; s.z += v.z; s.w += v.w;
  }
  ushort4 h, l;
  h.x = f2bf(s.x); l.x = f2bf(s.x - bf2f(h.x));
  h.y = f2bf(s.y); l.y = f2bf(s.y - bf2f(h.y));
  h.z = f2bf(s.z); l.z = f2bf(s.z - bf2f(h.z));
  h.w = f2bf(s.w); l.w = f2bf(s.w - bf2f(h.w));
  ((ushort4*)hi)[i] = h;
  ((ushort4*)lo)[i] = l;
}

// ---------------- 2-way causal split-K reduce -> bf16 cast ----------------
// P1 chunk covers k >= 2048: only valid (and only contributes) for rows >= 2048,
// i.e. float4 index >= rowsplit4.
__global__ __launch_bounds__(256) void reduce2_cast(const float* __restrict__ P0,
                                                    const float* __restrict__ P1,
                                                    u16* __restrict__ out,
                                                    int n4, int rowsplit4) {
  int i = blockIdx.x * 256 + threadIdx.x;
  if (i >= n4) return;
  float4 s = ((const float4*)P0)[i];
  if (i >= rowsplit4) {
    float4 v = ((const float4*)P1)[i];
    s.x += v.x; s.y += v.y; s.z += v.z; s.w += v.w;
  }
  ushort4 o;
  o.x = f2bf(s.x); o.y = f2bf(s.y); o.z = f2bf(s.z); o.w = f2bf(s.w);
  ((ushort4*)out)[i] = o;
}

// ---------------- 2-way split-K reduce -> fp32 ----------------
__global__ __launch_bounds__(256) void reduce2_f32(const float* __restrict__ P0,
                                                   const float* __restrict__ P1,
                                                   float* __restrict__ out, int n4) {
  int i = blockIdx.x * 256 + threadIdx.x;
  if (i >= n4) return;
  float4 a = ((const float4*)P0)[i];
  float4 b = ((const float4*)P1)[i];
  a.x += b.x; a.y += b.y; a.z += b.z; a.w += b.w;
  ((float4*)out)[i] = a;
}

// ---------------- x [4096,2048] fp32 -> xT [2048,4096] bf16 ----------------
__global__ __launch_bounds__(256) void transpose_cast(const float* __restrict__ X,
                                                      u16* __restrict__ XT) {
  __shared__ float tile[64][65];
  int db = blockIdx.x * 64, mb = blockIdx.y * 64;
  int tx = threadIdx.x & 63, ty = threadIdx.x >> 6;
#pragma unroll
  for (int r = 0; r < 16; ++r) {
    int row = ty * 16 + r;
    tile[row][tx] = X[(size_t)(mb + row) * DMODEL + db + tx];
  }
  __syncthreads();
#pragma unroll
  for (int r = 0; r < 16; ++r) {
    int row = ty * 16 + r;
    XT[(size_t)(db + row) * NCTX + mb + tx] = f2bf(tile[tx][row]);
  }
}

// ---------------- row softmax (fp32) -> bf16 attn, one expf pass ----------------
__global__ __launch_bounds__(256) void softmax_rows(const float* __restrict__ S,
                                                    u16* __restrict__ P) {
  int i = blockIdx.x;
  int t = threadIdx.x;
  __shared__ float rowbuf[NCTX];
  __shared__ float red[4];
  __shared__ float red2[4];
  const float* srow = S + (size_t)i * NCTX;
  int len = i + 1;
  int jmax = ((i >> 7) + 1) << 7;  // causal gemm reads j < 128*(bm+1)
  float mx = -3.0e38f;
  for (int j = t; j < len; j += 256) {
    float v = srow[j];
    rowbuf[j] = v;
    mx = fmaxf(mx, v);
  }
#pragma unroll
  for (int o = 32; o > 0; o >>= 1) mx = fmaxf(mx, __shfl_xor(mx, o, 64));
  if ((t & 63) == 0) red[t >> 6] = mx;
  __syncthreads();
  mx = fmaxf(fmaxf(red[0], red[1]), fmaxf(red[2], red[3]));
  float sum = 0.f;
  for (int j = t; j < len; j += 256) {
    float e = __expf(rowbuf[j] - mx);
    rowbuf[j] = e;
    sum += e;
  }
#pragma unroll
  for (int o = 32; o > 0; o >>= 1) sum += __shfl_xor(sum, o, 64);
  if ((t & 63) == 0) red2[t >> 6] = sum;
  __syncthreads();
  float inv = 1.0f / (red2[0] + red2[1] + red2[2] + red2[3]);
  u16* prow = P + (size_t)i * NCTX;
  for (int j = t; j < jmax; j += 256) {
    float v = (j < len) ? rowbuf[j] * inv : 0.0f;
    prow[j] = f2bf(v);
  }
}

// ---------------- bf16 MFMA GEMM, B^T layout, split-K -> per-chunk partials -------
// Chunk kc writes plain stores to C + kc*M*N. causal: K clipped to (bm+1)*128;
// chunk is skipped entirely if empty (reduce masks by row).
__global__ __launch_bounds__(256) void gemm_bt_p(const u16* __restrict__ A,
                                                 const u16* __restrict__ B,
                                                 float* __restrict__ C,
                                                 int M, int N, int K, int KC, int causal) {
  int bm = blockIdx.x, bn = blockIdx.y, kc = blockIdx.z;
  int kEnd = K;
  if (causal) { int ke = (bm + 1) * 128; if (ke < kEnd) kEnd = ke; }
  int kStart = kc * KC;
  if (kStart >= kEnd) return;
  int kStop = kStart + KC < kEnd ? kStart + KC : kEnd;
  __shared__ __align__(16) u16 As[128 * 32];
  __shared__ __align__(16) u16 Bs[128 * 32];
  int t = threadIdx.x;
  int lane = t & 63, w = t >> 6;
  int m0 = bm * 128, n0 = bn * 128;
  int wm = (w >> 1) * 64, wn = (w & 1) * 64;
  int mfrag = lane & 15, quad = lane >> 4;
  int srow = t >> 2, schunk = t & 3;
  float* Cc = C + (size_t)kc * M * N;
  f32x4 acc[4][4] = {};
  for (int kt = kStart; kt < kStop; kt += 32) {
#pragma unroll
    for (int p = 0; p < 2; ++p) {
      int row = p * 64 + srow;
      gl_lds16(A + (size_t)(m0 + row) * K + kt + schunk * 8, As + (size_t)(p * 256 + t) * 8);
      gl_lds16(B + (size_t)(n0 + row) * K + kt + schunk * 8, Bs + (size_t)(p * 256 + t) * 8);
    }
    __syncthreads();
    s16x8 af[4], bfr[4];
#pragma unroll
    for (int i = 0; i < 4; ++i)
      af[i] = *(const s16x8*)(As + (wm + i * 16 + mfrag) * 32 + quad * 8);
#pragma unroll
    for (int j = 0; j < 4; ++j)
      bfr[j] = *(const s16x8*)(Bs + (wn + j * 16 + mfrag) * 32 + quad * 8);
#pragma unroll
    for (int i = 0; i < 4; ++i)
#pragma unroll
      for (int j = 0; j < 4; ++j)
        acc[i][j] = __builtin_amdgcn_mfma_f32_16x16x32_bf16(af[i], bfr[j], acc[i][j], 0, 0, 0);
    __syncthreads();
  }
#pragma unroll
  for (int i = 0; i < 4; ++i)
#pragma unroll
    for (int j = 0; j < 4; ++j)
#pragma unroll
      for (int rr = 0; rr < 4; ++rr) {
        int row = m0 + wm + i * 16 + quad * 4 + rr;
        int col = n0 + wn + j * 16 + mfrag;
        Cc[(size_t)row * N + col] = acc[i][j][rr];
      }
}

// ---------------- bf16x3 split-precision MFMA GEMM, B^T, split-K partials --------
// C ~= (Ah+Al) @ (Bh+Bl)^T = Ah@Bh + Al@Bh + Ah@Bl  (fp32-accurate).
// Chunk kc writes plain stores to C + kc*chunkStride. causal: skip bn > bm tiles.
__global__ __launch_bounds__(256) void gemm_bt3_p(const u16* __restrict__ Ah,
                                                  const u16* __restrict__ Al,
                                                  const u16* __restrict__ Bh,
                                                  const u16* __restrict__ Bl,
                                                  float* __restrict__ C,
                                                  int lda, int ldb, int ldc,
                                                  int K, int KC, size_t chunkStride,
                                                  int causal) {
  int bm = blockIdx.x, bn = blockIdx.y, kc = blockIdx.z;
  if (causal && bn > bm) return;
  int kStart = kc * KC;
  if (kStart >= K) return;
  int kStop = kStart + KC < K ? kStart + KC : K;
  __shared__ __align__(16) u16 Ash[128 * 32];
  __shared__ __align__(16) u16 Asl[128 * 32];
  __shared__ __align__(16) u16 Bsh[128 * 32];
  __shared__ __align__(16) u16 Bsl[128 * 32];
  int t = threadIdx.x;
  int lane = t & 63, w = t >> 6;
  int m0 = bm * 128, n0 = bn * 128;
  int wm = (w >> 1) * 64, wn = (w & 1) * 64;
  int mfrag = lane & 15, quad = lane >> 4;
  int srow = t >> 2, schunk = t & 3;
  float* Cc = C + (size_t)kc * chunkStride;
  f32x4 acc[4][4] = {};
  for (int kt = kStart; kt < kStop; kt += 32) {
#pragma unroll
    for (int p = 0; p < 2; ++p) {
      int row = p * 64 + srow;
      size_t aoff = (size_t)(m0 + row) * lda + kt + schunk * 8;
      size_t boff = (size_t)(n0 + row) * ldb + kt + schunk * 8;
      size_t loff = (size_t)(p * 256 + t) * 8;
      gl_lds16(Ah + aoff, Ash + loff);
      gl_lds16(Al + aoff, Asl + loff);
      gl_lds16(Bh + boff, Bsh + loff);
      gl_lds16(Bl + boff, Bsl + loff);
    }
    __syncthreads();
    s16x8 a0[4], a1[4], b0[4];
#pragma unroll
    for (int i = 0; i < 4; ++i)
      a0[i] = *(const s16x8*)(Ash + (wm + i * 16 + mfrag) * 32 + quad * 8);
#pragma unroll
    for (int j = 0; j < 4; ++j)
      b0[j] = *(const s16x8*)(Bsh + (wn + j * 16 + mfrag) * 32 + quad * 8);
#pragma unroll
    for (int i = 0; i < 4; ++i)
#pragma unroll
      for (int j = 0; j < 4; ++j)
        acc[i][j] = __builtin_amdgcn_mfma_f32_16x16x32_bf16(a0[i], b0[j], acc[i][j], 0, 0, 0);
#pragma unroll
    for (int i = 0; i < 4; ++i)
      a1[i] = *(const s16x8*)(Asl + (wm + i * 16 + mfrag) * 32 + quad * 8);
#pragma unroll
    for (int i = 0; i < 4; ++i)
#pragma unroll
      for (int j = 0; j < 4; ++j)
        acc[i][j] = __builtin_amdgcn_mfma_f32_16x16x32_bf16(a1[i], b0[j], acc[i][j], 0, 0, 0);
#pragma unroll
    for (int j = 0; j < 4; ++j)
      b0[j] = *(const s16x8*)(Bsl + (wn + j * 16 + mfrag) * 32 + quad * 8);
#pragma unroll
    for (int i = 0; i < 4; ++i)
#pragma unroll
      for (int j = 0; j < 4; ++j)
        acc[i][j] = __builtin_amdgcn_mfma_f32_16x16x32_bf16(a0[i], b0[j], acc[i][j], 0, 0, 0);
    __syncthreads();
  }
#pragma unroll
  for (int i = 0; i < 4; ++i)
#pragma unroll
    for (int j = 0; j < 4; ++j)
#pragma unroll
      for (int rr = 0; rr < 4; ++rr) {
        int row = m0 + wm + i * 16 + quad * 4 + rr;
        int col = n0 + wn + j * 16 + mfrag;
        Cc[(size_t)row * ldc + col] = acc[i][j][rr];
      }
}

extern "C" void kernel_launch(void* const* d_in, const int* in_sizes, int n_in,
                              void* d_out, int out_size, void* d_ws, size_t ws_size,
                              hipStream_t stream) {
  const float* x  = (const float*)d_in[0];
  const float* Wk = (const float*)d_in[1];
  const float* Wq = (const float*)d_in[2];
  const float* W2 = (const float*)d_in[3];

  char* ws = (char*)d_ws;
  const size_t MB = 1024 * 1024;
  // persistent region [0, 78 MB)
  u16*   QKh  = (u16*)  (ws + 0);            //  2 MB  [4096,256] hi
  u16*   QKl  = (u16*)  (ws + 2 * MB);       //  2 MB  lo
  u16*   Wh   = (u16*)  (ws + 4 * MB);       //  1 MB  [256,2048] (Wq ; Wk) hi
  u16*   Wl   = (u16*)  (ws + 5 * MB);       //  1 MB  lo
  u16*   xT   = (u16*)  (ws + 6 * MB);       // 16 MB  [2048,4096] bf16
  u16*   W2b  = (u16*)  (ws + 22 * MB);      //  8 MB  [2048,2048] bf16
  u16*   outb = (u16*)  (ws + 30 * MB);      // 16 MB  [4096,2048] bf16
  u16*   attn = (u16*)  (ws + 46 * MB);      // 32 MB  [4096,4096] bf16
  // reusable region A [78, 142 MB) — lifetimes strictly sequential:
  u16*   xh   = (u16*)  (ws + 78 * MB);      // 16 MB  (dead after qk gemm)
  u16*   xl   = (u16*)  (ws + 94 * MB);      // 16 MB  (dead after qk gemm)
  float* QKp  = (float*)(ws + 110 * MB);     // 32 MB  8 x [4096,256] partials
  float* S    = (float*)(ws + 78 * MB);      // 64 MB  scores (after xh/xl/QKp dead)
  float* P0   = (float*)(ws + 78 * MB);      // 32 MB  attn@x partial k<2048 (after S dead)
  float* P1   = (float*)(ws + 110 * MB);     // 32 MB  attn@x partial k>=2048
  // P0/P1 then reused as the final GEMM's partials.

  const int XN4 = NCTX * DMODEL / 4;
  const int WN4 = DHEAD * DMODEL / 4;
  const int QKN4 = NCTX * 256 / 4;

  // precision-critical path: bf16x3 splits
  split_f32_bf16x2<<<(XN4 + 255) / 256, 256, 0, stream>>>(x, xh, xl, XN4);
  split_f32_bf16x2<<<(WN4 + 255) / 256, 256, 0, stream>>>(Wq, Wh, Wl, WN4);
  split_f32_bf16x2<<<(WN4 + 255) / 256, 256, 0, stream>>>(Wk, Wh + (size_t)DHEAD * DMODEL,
                                                          Wl + (size_t)DHEAD * DMODEL, WN4);
  cast_f32_bf16<<<(2048 * 2048 / 4 + 255) / 256, 256, 0, stream>>>(W2, W2b, 2048 * 2048 / 4);
  transpose_cast<<<dim3(DMODEL / 64, NCTX / 64), 256, 0, stream>>>(x, xT);

  // q,k = x @ [Wq;Wk]^T via bf16x3, split-K KC=256 -> 512 blocks, 8 partials
  gemm_bt3_p<<<dim3(NCTX / 128, 2, 8), 256, 0, stream>>>(
      xh, xl, Wh, Wl, QKp, DMODEL, DMODEL, 256, DMODEL, 256, (size_t)NCTX * 256, 0);
  reduce8_split<<<(QKN4 + 255) / 256, 256, 0, stream>>>(QKp, QKh, QKl, QKN4);

  // scores = q @ k^T (lower-triangular tiles), K=128: single chunk, direct store
  gemm_bt3_p<<<dim3(NCTX / 128, NCTX / 128, 1), 256, 0, stream>>>(
      QKh, QKl, QKh + DHEAD, QKl + DHEAD, S, 256, 256, NCTX, DHEAD, DHEAD, 0, 1);
  softmax_rows<<<NCTX, 256, 0, stream>>>(S, attn);

  // out = attn @ x (causal), split-K KC=2048 -> 768 active blocks, 2 partials
  gemm_bt_p<<<dim3(NCTX / 128, DMODEL / 128, 2), 256, 0, stream>>>(
      attn, xT, P0, NCTX, DMODEL, NCTX, 2048, 1);
  reduce2_cast<<<(XN4 + 255) / 256, 256, 0, stream>>>(P0, P1, outb, XN4,
                                                      2048 * 2048 / 4);

  // final = out @ W2^T, split-K KC=1024 -> 1024 blocks, 2 partials
  gemm_bt_p<<<dim3(NCTX / 128, DMODEL / 128, 2), 256, 0, stream>>>(
      outb, W2b, P0, NCTX, DMODEL, DMODEL, 1024, 0);
  reduce2_f32<<<(XN4 + 255) / 256, 256, 0, stream>>>(P0, P1, (float*)d_out, XN4);
}

// Round 5
// 313.546 us; speedup vs baseline: 1.3524x; 1.1630x over previous
//
#include <hip/hip_runtime.h>

#define NCTX 4096
#define DMODEL 2048
#define DHEAD 128

typedef short s16x8 __attribute__((ext_vector_type(8)));
typedef float f32x4 __attribute__((ext_vector_type(4)));
typedef unsigned short u16;

__device__ __forceinline__ u16 f2bf(float f) {
  union { float f; unsigned u; } v; v.f = f;
  unsigned u = v.u;
  return (u16)((u + 0x7FFFu + ((u >> 16) & 1u)) >> 16);
}
__device__ __forceinline__ float bf2f(u16 h) {
  union { unsigned u; float f; } v; v.u = ((unsigned)h) << 16; return v.f;
}

__device__ __forceinline__ void gl_lds16(const void* g, void* l) {
  __builtin_amdgcn_global_load_lds((const __attribute__((address_space(1))) void*)g,
                                   (__attribute__((address_space(3))) void*)l, 16, 0, 0);
}

// ---------------- elementwise fp32 -> bf16 cast ----------------
__global__ __launch_bounds__(256) void cast_f32_bf16(const float* __restrict__ in,
                                                     u16* __restrict__ out, int n4) {
  int i = blockIdx.x * 256 + threadIdx.x;
  if (i >= n4) return;
  float4 v = ((const float4*)in)[i];
  ushort4 o;
  o.x = f2bf(v.x); o.y = f2bf(v.y); o.z = f2bf(v.z); o.w = f2bf(v.w);
  ((ushort4*)out)[i] = o;
}

// ---------------- fp32 -> (hi, lo) bf16 split ----------------
__global__ __launch_bounds__(256) void split_f32_bf16x2(const float* __restrict__ in,
                                                        u16* __restrict__ hi,
                                                        u16* __restrict__ lo, int n4) {
  int i = blockIdx.x * 256 + threadIdx.x;
  if (i >= n4) return;
  float4 v = ((const float4*)in)[i];
  ushort4 h, l;
  h.x = f2bf(v.x); l.x = f2bf(v.x - bf2f(h.x));
  h.y = f2bf(v.y); l.y = f2bf(v.y - bf2f(h.y));
  h.z = f2bf(v.z); l.z = f2bf(v.z - bf2f(h.z));
  h.w = f2bf(v.w); l.w = f2bf(v.w - bf2f(h.w));
  ((ushort4*)hi)[i] = h;
  ((ushort4*)lo)[i] = l;
}

// ---------------- 8-way split-K reduce -> (hi, lo) bf16 split ----------------
__global__ __launch_bounds__(256) void reduce8_split(const float* __restrict__ P,
                                                     u16* __restrict__ hi,
                                                     u16* __restrict__ lo, int n4) {
  int i = blockIdx.x * 256 + threadIdx.x;
  if (i >= n4) return;
  float4 s = ((const float4*)P)[i];
#pragma unroll
  for (int z = 1; z < 8; ++z) {
    float4 v = ((const float4*)P)[(size_t)z * n4 + i];
    s.x += v.x; s.y += v.y; s.z += v.z; s.w += v.w;
  }
  ushort4 h, l;
  h.x = f2bf(s.x); l.x = f2bf(s.x - bf2f(h.x));
  h.y = f2bf(s.y); l.y = f2bf(s.y - bf2f(h.y));
  h.z = f2bf(s.z); l.z = f2bf(s.z - bf2f(h.z));
  h.w = f2bf(s.w); l.w = f2bf(s.w - bf2f(h.w));
  ((ushort4*)hi)[i] = h;
  ((ushort4*)lo)[i] = l;
}

// ---------------- 2-way causal split-K reduce -> bf16 cast ----------------
__global__ __launch_bounds__(256) void reduce2_cast(const float* __restrict__ P0,
                                                    const float* __restrict__ P1,
                                                    u16* __restrict__ out,
                                                    int n4, int rowsplit4) {
  int i = blockIdx.x * 256 + threadIdx.x;
  if (i >= n4) return;
  float4 s = ((const float4*)P0)[i];
  if (i >= rowsplit4) {
    float4 v = ((const float4*)P1)[i];
    s.x += v.x; s.y += v.y; s.z += v.z; s.w += v.w;
  }
  ushort4 o;
  o.x = f2bf(s.x); o.y = f2bf(s.y); o.z = f2bf(s.z); o.w = f2bf(s.w);
  ((ushort4*)out)[i] = o;
}

// ---------------- 2-way split-K reduce -> fp32 ----------------
__global__ __launch_bounds__(256) void reduce2_f32(const float* __restrict__ P0,
                                                   const float* __restrict__ P1,
                                                   float* __restrict__ out, int n4) {
  int i = blockIdx.x * 256 + threadIdx.x;
  if (i >= n4) return;
  float4 a = ((const float4*)P0)[i];
  float4 b = ((const float4*)P1)[i];
  a.x += b.x; a.y += b.y; a.z += b.z; a.w += b.w;
  ((float4*)out)[i] = a;
}

// ---------------- x [4096,2048] fp32 -> xT [2048,4096] bf16 ----------------
__global__ __launch_bounds__(256) void transpose_cast(const float* __restrict__ X,
                                                      u16* __restrict__ XT) {
  __shared__ float tile[64][65];
  int db = blockIdx.x * 64, mb = blockIdx.y * 64;
  int tx = threadIdx.x & 63, ty = threadIdx.x >> 6;
#pragma unroll
  for (int r = 0; r < 16; ++r) {
    int row = ty * 16 + r;
    tile[row][tx] = X[(size_t)(mb + row) * DMODEL + db + tx];
  }
  __syncthreads();
#pragma unroll
  for (int r = 0; r < 16; ++r) {
    int row = ty * 16 + r;
    XT[(size_t)(db + row) * NCTX + mb + tx] = f2bf(tile[tx][row]);
  }
}

// ---------------- row softmax (fp32) -> bf16 attn, one expf pass ----------------
__global__ __launch_bounds__(256) void softmax_rows(const float* __restrict__ S,
                                                    u16* __restrict__ P) {
  int i = blockIdx.x;
  int t = threadIdx.x;
  __shared__ float rowbuf[NCTX];
  __shared__ float red[4];
  __shared__ float red2[4];
  const float* srow = S + (size_t)i * NCTX;
  int len = i + 1;
  int jmax = ((i >> 7) + 1) << 7;  // causal gemm reads j < 128*(bm+1)
  float mx = -3.0e38f;
  for (int j = t; j < len; j += 256) {
    float v = srow[j];
    rowbuf[j] = v;
    mx = fmaxf(mx, v);
  }
#pragma unroll
  for (int o = 32; o > 0; o >>= 1) mx = fmaxf(mx, __shfl_xor(mx, o, 64));
  if ((t & 63) == 0) red[t >> 6] = mx;
  __syncthreads();
  mx = fmaxf(fmaxf(red[0], red[1]), fmaxf(red[2], red[3]));
  float sum = 0.f;
  for (int j = t; j < len; j += 256) {
    float e = __expf(rowbuf[j] - mx);
    rowbuf[j] = e;
    sum += e;
  }
#pragma unroll
  for (int o = 32; o > 0; o >>= 1) sum += __shfl_xor(sum, o, 64);
  if ((t & 63) == 0) red2[t >> 6] = sum;
  __syncthreads();
  float inv = 1.0f / (red2[0] + red2[1] + red2[2] + red2[3]);
  u16* prow = P + (size_t)i * NCTX;
  for (int j = t; j < jmax; j += 256) {
    float v = (j < len) ? rowbuf[j] * inv : 0.0f;
    prow[j] = f2bf(v);
  }
}

// ---------------- bf16 MFMA GEMM, B^T layout, split-K -> per-chunk partials -------
// __launch_bounds__(256,4): cap regs at 128 (incl 64 acc AGPRs) -> 4 blocks/CU.
// Heavy-first bm order (bm = gridX-1-bx) shrinks the causal imbalance tail.
__global__ __launch_bounds__(256, 4) void gemm_bt_p(const u16* __restrict__ A,
                                                    const u16* __restrict__ B,
                                                    float* __restrict__ C,
                                                    int M, int N, int K, int KC, int causal) {
  int bm = gridDim.x - 1 - blockIdx.x, bn = blockIdx.y, kc = blockIdx.z;
  int kEnd = K;
  if (causal) { int ke = (bm + 1) * 128; if (ke < kEnd) kEnd = ke; }
  int kStart = kc * KC;
  if (kStart >= kEnd) return;
  int kStop = kStart + KC < kEnd ? kStart + KC : kEnd;
  __shared__ __align__(16) u16 As[128 * 32];
  __shared__ __align__(16) u16 Bs[128 * 32];
  int t = threadIdx.x;
  int lane = t & 63, w = t >> 6;
  int m0 = bm * 128, n0 = bn * 128;
  int wm = (w >> 1) * 64, wn = (w & 1) * 64;
  int mfrag = lane & 15, quad = lane >> 4;
  int srow = t >> 2, schunk = t & 3;
  float* Cc = C + (size_t)kc * M * N;
  f32x4 acc[4][4] = {};
  for (int kt = kStart; kt < kStop; kt += 32) {
#pragma unroll
    for (int p = 0; p < 2; ++p) {
      int row = p * 64 + srow;
      gl_lds16(A + (size_t)(m0 + row) * K + kt + schunk * 8, As + (size_t)(p * 256 + t) * 8);
      gl_lds16(B + (size_t)(n0 + row) * K + kt + schunk * 8, Bs + (size_t)(p * 256 + t) * 8);
    }
    __syncthreads();
    s16x8 af[4], bfr[4];
#pragma unroll
    for (int i = 0; i < 4; ++i)
      af[i] = *(const s16x8*)(As + (wm + i * 16 + mfrag) * 32 + quad * 8);
#pragma unroll
    for (int j = 0; j < 4; ++j)
      bfr[j] = *(const s16x8*)(Bs + (wn + j * 16 + mfrag) * 32 + quad * 8);
#pragma unroll
    for (int i = 0; i < 4; ++i)
#pragma unroll
      for (int j = 0; j < 4; ++j)
        acc[i][j] = __builtin_amdgcn_mfma_f32_16x16x32_bf16(af[i], bfr[j], acc[i][j], 0, 0, 0);
    __syncthreads();
  }
#pragma unroll
  for (int i = 0; i < 4; ++i)
#pragma unroll
    for (int j = 0; j < 4; ++j)
#pragma unroll
      for (int rr = 0; rr < 4; ++rr) {
        int row = m0 + wm + i * 16 + quad * 4 + rr;
        int col = n0 + wn + j * 16 + mfrag;
        Cc[(size_t)row * N + col] = acc[i][j][rr];
      }
}

// ---------------- bf16x3 split-precision MFMA GEMM, B^T, split-K partials --------
__global__ __launch_bounds__(256, 3) void gemm_bt3_p(const u16* __restrict__ Ah,
                                                     const u16* __restrict__ Al,
                                                     const u16* __restrict__ Bh,
                                                     const u16* __restrict__ Bl,
                                                     float* __restrict__ C,
                                                     int lda, int ldb, int ldc,
                                                     int K, int KC, size_t chunkStride,
                                                     int causal) {
  int bm = gridDim.x - 1 - blockIdx.x, bn = blockIdx.y, kc = blockIdx.z;
  if (causal && bn > bm) return;
  int kStart = kc * KC;
  if (kStart >= K) return;
  int kStop = kStart + KC < K ? kStart + KC : K;
  __shared__ __align__(16) u16 Ash[128 * 32];
  __shared__ __align__(16) u16 Asl[128 * 32];
  __shared__ __align__(16) u16 Bsh[128 * 32];
  __shared__ __align__(16) u16 Bsl[128 * 32];
  int t = threadIdx.x;
  int lane = t & 63, w = t >> 6;
  int m0 = bm * 128, n0 = bn * 128;
  int wm = (w >> 1) * 64, wn = (w & 1) * 64;
  int mfrag = lane & 15, quad = lane >> 4;
  int srow = t >> 2, schunk = t & 3;
  float* Cc = C + (size_t)kc * chunkStride;
  f32x4 acc[4][4] = {};
  for (int kt = kStart; kt < kStop; kt += 32) {
#pragma unroll
    for (int p = 0; p < 2; ++p) {
      int row = p * 64 + srow;
      size_t aoff = (size_t)(m0 + row) * lda + kt + schunk * 8;
      size_t boff = (size_t)(n0 + row) * ldb + kt + schunk * 8;
      size_t loff = (size_t)(p * 256 + t) * 8;
      gl_lds16(Ah + aoff, Ash + loff);
      gl_lds16(Al + aoff, Asl + loff);
      gl_lds16(Bh + boff, Bsh + loff);
      gl_lds16(Bl + boff, Bsl + loff);
    }
    __syncthreads();
    s16x8 a0[4], a1[4], b0[4];
#pragma unroll
    for (int i = 0; i < 4; ++i)
      a0[i] = *(const s16x8*)(Ash + (wm + i * 16 + mfrag) * 32 + quad * 8);
#pragma unroll
    for (int j = 0; j < 4; ++j)
      b0[j] = *(const s16x8*)(Bsh + (wn + j * 16 + mfrag) * 32 + quad * 8);
#pragma unroll
    for (int i = 0; i < 4; ++i)
#pragma unroll
      for (int j = 0; j < 4; ++j)
        acc[i][j] = __builtin_amdgcn_mfma_f32_16x16x32_bf16(a0[i], b0[j], acc[i][j], 0, 0, 0);
#pragma unroll
    for (int i = 0; i < 4; ++i)
      a1[i] = *(const s16x8*)(Asl + (wm + i * 16 + mfrag) * 32 + quad * 8);
#pragma unroll
    for (int i = 0; i < 4; ++i)
#pragma unroll
      for (int j = 0; j < 4; ++j)
        acc[i][j] = __builtin_amdgcn_mfma_f32_16x16x32_bf16(a1[i], b0[j], acc[i][j], 0, 0, 0);
#pragma unroll
    for (int j = 0; j < 4; ++j)
      b0[j] = *(const s16x8*)(Bsl + (wn + j * 16 + mfrag) * 32 + quad * 8);
#pragma unroll
    for (int i = 0; i < 4; ++i)
#pragma unroll
      for (int j = 0; j < 4; ++j)
        acc[i][j] = __builtin_amdgcn_mfma_f32_16x16x32_bf16(a0[i], b0[j], acc[i][j], 0, 0, 0);
    __syncthreads();
  }
#pragma unroll
  for (int i = 0; i < 4; ++i)
#pragma unroll
    for (int j = 0; j < 4; ++j)
#pragma unroll
      for (int rr = 0; rr < 4; ++rr) {
        int row = m0 + wm + i * 16 + quad * 4 + rr;
        int col = n0 + wn + j * 16 + mfrag;
        Cc[(size_t)row * ldc + col] = acc[i][j][rr];
      }
}

extern "C" void kernel_launch(void* const* d_in, const int* in_sizes, int n_in,
                              void* d_out, int out_size, void* d_ws, size_t ws_size,
                              hipStream_t stream) {
  const float* x  = (const float*)d_in[0];
  const float* Wk = (const float*)d_in[1];
  const float* Wq = (const float*)d_in[2];
  const float* W2 = (const float*)d_in[3];

  char* ws = (char*)d_ws;
  const size_t MB = 1024 * 1024;
  // persistent region [0, 78 MB)
  u16*   QKh  = (u16*)  (ws + 0);            //  2 MB  [4096,256] hi
  u16*   QKl  = (u16*)  (ws + 2 * MB);       //  2 MB  lo
  u16*   Wh   = (u16*)  (ws + 4 * MB);       //  1 MB  [256,2048] (Wq ; Wk) hi
  u16*   Wl   = (u16*)  (ws + 5 * MB);       //  1 MB  lo
  u16*   xT   = (u16*)  (ws + 6 * MB);       // 16 MB  [2048,4096] bf16
  u16*   W2b  = (u16*)  (ws + 22 * MB);      //  8 MB  [2048,2048] bf16
  u16*   outb = (u16*)  (ws + 30 * MB);      // 16 MB  [4096,2048] bf16
  u16*   attn = (u16*)  (ws + 46 * MB);      // 32 MB  [4096,4096] bf16
  // reusable region A [78, 142 MB) — lifetimes strictly sequential:
  u16*   xh   = (u16*)  (ws + 78 * MB);      // 16 MB  (dead after qk gemm)
  u16*   xl   = (u16*)  (ws + 94 * MB);      // 16 MB  (dead after qk gemm)
  float* QKp  = (float*)(ws + 110 * MB);     // 32 MB  8 x [4096,256] partials
  float* S    = (float*)(ws + 78 * MB);      // 64 MB  scores (after xh/xl/QKp dead)
  float* P0   = (float*)(ws + 78 * MB);      // 32 MB  attn@x partial k<2048 (after S dead)
  float* P1   = (float*)(ws + 110 * MB);     // 32 MB  attn@x partial k>=2048
  // P0/P1 then reused as the final GEMM's partials.

  const int XN4 = NCTX * DMODEL / 4;
  const int WN4 = DHEAD * DMODEL / 4;
  const int QKN4 = NCTX * 256 / 4;

  // precision-critical path: bf16x3 splits
  split_f32_bf16x2<<<(XN4 + 255) / 256, 256, 0, stream>>>(x, xh, xl, XN4);
  split_f32_bf16x2<<<(WN4 + 255) / 256, 256, 0, stream>>>(Wq, Wh, Wl, WN4);
  split_f32_bf16x2<<<(WN4 + 255) / 256, 256, 0, stream>>>(Wk, Wh + (size_t)DHEAD * DMODEL,
                                                          Wl + (size_t)DHEAD * DMODEL, WN4);
  cast_f32_bf16<<<(2048 * 2048 / 4 + 255) / 256, 256, 0, stream>>>(W2, W2b, 2048 * 2048 / 4);
  transpose_cast<<<dim3(DMODEL / 64, NCTX / 64), 256, 0, stream>>>(x, xT);

  // q,k = x @ [Wq;Wk]^T via bf16x3, split-K KC=256 -> 512 blocks, 8 partials
  gemm_bt3_p<<<dim3(NCTX / 128, 2, 8), 256, 0, stream>>>(
      xh, xl, Wh, Wl, QKp, DMODEL, DMODEL, 256, DMODEL, 256, (size_t)NCTX * 256, 0);
  reduce8_split<<<(QKN4 + 255) / 256, 256, 0, stream>>>(QKp, QKh, QKl, QKN4);

  // scores = q @ k^T (lower-triangular tiles), K=128: single chunk, direct store
  gemm_bt3_p<<<dim3(NCTX / 128, NCTX / 128, 1), 256, 0, stream>>>(
      QKh, QKl, QKh + DHEAD, QKl + DHEAD, S, 256, 256, NCTX, DHEAD, DHEAD, 0, 1);
  softmax_rows<<<NCTX, 256, 0, stream>>>(S, attn);

  // out = attn @ x (causal), split-K KC=2048 -> 768 active blocks, 2 partials
  gemm_bt_p<<<dim3(NCTX / 128, DMODEL / 128, 2), 256, 0, stream>>>(
      attn, xT, P0, NCTX, DMODEL, NCTX, 2048, 1);
  reduce2_cast<<<(XN4 + 255) / 256, 256, 0, stream>>>(P0, P1, outb, XN4,
                                                      2048 * 2048 / 4);

  // final = out @ W2^T, split-K KC=1024 -> 1024 blocks, 2 partials
  gemm_bt_p<<<dim3(NCTX / 128, DMODEL / 128, 2), 256, 0, stream>>>(
      outb, W2b, P0, NCTX, DMODEL, DMODEL, 1024, 0);
  reduce2_f32<<<(XN4 + 255) / 256, 256, 0, stream>>>(P0, P1, (float*)d_out, XN4);
}

// Round 6
// 287.648 us; speedup vs baseline: 1.4742x; 1.0900x over previous
//
#include <hip/hip_runtime.h>

#define NCTX 4096
#define DMODEL 2048
#define DHEAD 128

typedef short s16x8 __attribute__((ext_vector_type(8)));
typedef float f32x4 __attribute__((ext_vector_type(4)));
typedef unsigned short u16;

__device__ __forceinline__ u16 f2bf(float f) {
  union { float f; unsigned u; } v; v.f = f;
  unsigned u = v.u;
  return (u16)((u + 0x7FFFu + ((u >> 16) & 1u)) >> 16);
}
__device__ __forceinline__ float bf2f(u16 h) {
  union { unsigned u; float f; } v; v.u = ((unsigned)h) << 16; return v.f;
}

__device__ __forceinline__ void gl_lds16(const void* g, void* l) {
  __builtin_amdgcn_global_load_lds((const __attribute__((address_space(1))) void*)g,
                                   (__attribute__((address_space(3))) void*)l, 16, 0, 0);
}

__device__ __forceinline__ void split4(float4 v, ushort4& h, ushort4& l) {
  h.x = f2bf(v.x); l.x = f2bf(v.x - bf2f(h.x));
  h.y = f2bf(v.y); l.y = f2bf(v.y - bf2f(h.y));
  h.z = f2bf(v.z); l.z = f2bf(v.z - bf2f(h.z));
  h.w = f2bf(v.w); l.w = f2bf(v.w - bf2f(h.w));
}

// ---------------- fused prep: x split | Wq split | Wk split | W2 cast | x transpose ----
// block ranges: [0,8192) x-split, [8192,8448) Wq, [8448,8704) Wk,
//               [8704,12800) W2 cast, [12800,14848) transpose (2048 blocks).
__global__ __launch_bounds__(256) void prep_all(const float* __restrict__ x,
                                                const float* __restrict__ Wq,
                                                const float* __restrict__ Wk,
                                                const float* __restrict__ W2,
                                                u16* __restrict__ xh, u16* __restrict__ xl,
                                                u16* __restrict__ Wh, u16* __restrict__ Wl,
                                                u16* __restrict__ W2b, u16* __restrict__ XT) {
  __shared__ float tile[64][65];
  int b = blockIdx.x;
  int t = threadIdx.x;
  if (b < 8192) {                      // split x: 8M elems = 2M float4
    int i = b * 256 + t;
    float4 v = ((const float4*)x)[i];
    ushort4 h, l; split4(v, h, l);
    ((ushort4*)xh)[i] = h; ((ushort4*)xl)[i] = l;
  } else if (b < 8704) {               // split Wq / Wk: 64K float4 each
    int wk = (b >= 8448);
    int i = (b - (wk ? 8448 : 8192)) * 256 + t;
    const float* W = wk ? Wk : Wq;
    size_t off = wk ? ((size_t)DHEAD * DMODEL / 4) : 0;
    float4 v = ((const float4*)W)[i];
    ushort4 h, l; split4(v, h, l);
    ((ushort4*)Wh)[off + i] = h; ((ushort4*)Wl)[off + i] = l;
  } else if (b < 12800) {              // cast W2: 1M float4
    int i = (b - 8704) * 256 + t;
    float4 v = ((const float4*)W2)[i];
    ushort4 o;
    o.x = f2bf(v.x); o.y = f2bf(v.y); o.z = f2bf(v.z); o.w = f2bf(v.w);
    ((ushort4*)W2b)[i] = o;
  } else {                             // transpose x -> XT bf16
    int bb = b - 12800;
    int db = (bb & 31) * 64, mb = (bb >> 5) * 64;
    int tx = t & 63, ty = t >> 6;
#pragma unroll
    for (int r = 0; r < 16; ++r) {
      int row = ty * 16 + r;
      tile[row][tx] = x[(size_t)(mb + row) * DMODEL + db + tx];
    }
    __syncthreads();
#pragma unroll
    for (int r = 0; r < 16; ++r) {
      int row = ty * 16 + r;
      XT[(size_t)(db + row) * NCTX + mb + tx] = f2bf(tile[tx][row]);
    }
  }
}

// ---------------- 8-way split-K reduce -> (hi, lo) bf16 split ----------------
__global__ __launch_bounds__(256) void reduce8_split(const float* __restrict__ P,
                                                     u16* __restrict__ hi,
                                                     u16* __restrict__ lo, int n4) {
  int i = blockIdx.x * 256 + threadIdx.x;
  if (i >= n4) return;
  float4 s = ((const float4*)P)[i];
#pragma unroll
  for (int z = 1; z < 8; ++z) {
    float4 v = ((const float4*)P)[(size_t)z * n4 + i];
    s.x += v.x; s.y += v.y; s.z += v.z; s.w += v.w;
  }
  ushort4 h, l; split4(s, h, l);
  ((ushort4*)hi)[i] = h;
  ((ushort4*)lo)[i] = l;
}

// ---------------- 2-way causal split-K reduce -> bf16 cast ----------------
__global__ __launch_bounds__(256) void reduce2_cast(const float* __restrict__ P0,
                                                    const float* __restrict__ P1,
                                                    u16* __restrict__ out,
                                                    int n4, int rowsplit4) {
  int i = blockIdx.x * 256 + threadIdx.x;
  if (i >= n4) return;
  float4 s = ((const float4*)P0)[i];
  if (i >= rowsplit4) {
    float4 v = ((const float4*)P1)[i];
    s.x += v.x; s.y += v.y; s.z += v.z; s.w += v.w;
  }
  ushort4 o;
  o.x = f2bf(s.x); o.y = f2bf(s.y); o.z = f2bf(s.z); o.w = f2bf(s.w);
  ((ushort4*)out)[i] = o;
}

// ---------------- 2-way split-K reduce -> fp32 ----------------
__global__ __launch_bounds__(256) void reduce2_f32(const float* __restrict__ P0,
                                                   const float* __restrict__ P1,
                                                   float* __restrict__ out, int n4) {
  int i = blockIdx.x * 256 + threadIdx.x;
  if (i >= n4) return;
  float4 a = ((const float4*)P0)[i];
  float4 b = ((const float4*)P1)[i];
  a.x += b.x; a.y += b.y; a.z += b.z; a.w += b.w;
  ((float4*)out)[i] = a;
}

// ---------------- row softmax (fp32) -> bf16 attn, one expf pass ----------------
__global__ __launch_bounds__(256) void softmax_rows(const float* __restrict__ S,
                                                    u16* __restrict__ P) {
  int i = blockIdx.x;
  int t = threadIdx.x;
  __shared__ float rowbuf[NCTX];
  __shared__ float red[4];
  __shared__ float red2[4];
  const float* srow = S + (size_t)i * NCTX;
  int len = i + 1;
  int jmax = ((i >> 7) + 1) << 7;  // causal gemm reads j < 128*(bm+1)
  float mx = -3.0e38f;
  for (int j = t; j < len; j += 256) {
    float v = srow[j];
    rowbuf[j] = v;
    mx = fmaxf(mx, v);
  }
#pragma unroll
  for (int o = 32; o > 0; o >>= 1) mx = fmaxf(mx, __shfl_xor(mx, o, 64));
  if ((t & 63) == 0) red[t >> 6] = mx;
  __syncthreads();
  mx = fmaxf(fmaxf(red[0], red[1]), fmaxf(red[2], red[3]));
  float sum = 0.f;
  for (int j = t; j < len; j += 256) {
    float e = __expf(rowbuf[j] - mx);
    rowbuf[j] = e;
    sum += e;
  }
#pragma unroll
  for (int o = 32; o > 0; o >>= 1) sum += __shfl_xor(sum, o, 64);
  if ((t & 63) == 0) red2[t >> 6] = sum;
  __syncthreads();
  float inv = 1.0f / (red2[0] + red2[1] + red2[2] + red2[3]);
  u16* prow = P + (size_t)i * NCTX;
  for (int j = t; j < jmax; j += 256) {
    float v = (j < len) ? rowbuf[j] * inv : 0.0f;
    prow[j] = f2bf(v);
  }
}

// ---------------- bf16 MFMA GEMM, B^T layout, BK=64, XOR-swizzled LDS -------------
// split-K -> per-chunk partials (plain stores). __launch_bounds__(256,4) -> 4 blk/CU
// (LDS 32 KB x 4 = 128 <= 160 KB). Lane loads global chunk schunk^(row&7) so the
// linear global_load_lds dest yields a bank-conflict-free fragment-read layout.
__global__ __launch_bounds__(256, 4) void gemm_bt_p(const u16* __restrict__ A,
                                                    const u16* __restrict__ B,
                                                    float* __restrict__ C,
                                                    int M, int N, int K, int KC, int causal) {
  int bm = gridDim.x - 1 - blockIdx.x, bn = blockIdx.y, kc = blockIdx.z;
  int kEnd = K;
  if (causal) { int ke = (bm + 1) * 128; if (ke < kEnd) kEnd = ke; }
  int kStart = kc * KC;
  if (kStart >= kEnd) return;
  int kStop = kStart + KC < kEnd ? kStart + KC : kEnd;
  __shared__ __align__(16) u16 As[128 * 64];
  __shared__ __align__(16) u16 Bs[128 * 64];
  int t = threadIdx.x;
  int lane = t & 63, w = t >> 6;
  int m0 = bm * 128, n0 = bn * 128;
  int wm = (w >> 1) * 64, wn = (w & 1) * 64;
  int mfrag = lane & 15, quad = lane >> 4;
  int srow = t >> 3, schunk = t & 7;
  int rsw = mfrag & 7;
  float* Cc = C + (size_t)kc * M * N;
  f32x4 acc[4][4] = {};
  for (int kt = kStart; kt < kStop; kt += 64) {
#pragma unroll
    for (int p = 0; p < 4; ++p) {
      int row = p * 32 + srow;
      int gsc = schunk ^ (row & 7);
      gl_lds16(A + (size_t)(m0 + row) * K + kt + gsc * 8, As + (size_t)(p * 256 + t) * 8);
      gl_lds16(B + (size_t)(n0 + row) * K + kt + gsc * 8, Bs + (size_t)(p * 256 + t) * 8);
    }
    __syncthreads();
#pragma unroll
    for (int ks = 0; ks < 2; ++ks) {
      int c0 = ((ks * 4 + quad) ^ rsw) * 8;
      s16x8 af[4], bfr[4];
#pragma unroll
      for (int i = 0; i < 4; ++i)
        af[i] = *(const s16x8*)(As + (wm + i * 16 + mfrag) * 64 + c0);
#pragma unroll
      for (int j = 0; j < 4; ++j)
        bfr[j] = *(const s16x8*)(Bs + (wn + j * 16 + mfrag) * 64 + c0);
#pragma unroll
      for (int i = 0; i < 4; ++i)
#pragma unroll
        for (int j = 0; j < 4; ++j)
          acc[i][j] = __builtin_amdgcn_mfma_f32_16x16x32_bf16(af[i], bfr[j], acc[i][j], 0, 0, 0);
    }
    __syncthreads();
  }
#pragma unroll
  for (int i = 0; i < 4; ++i)
#pragma unroll
    for (int j = 0; j < 4; ++j)
#pragma unroll
      for (int rr = 0; rr < 4; ++rr) {
        int row = m0 + wm + i * 16 + quad * 4 + rr;
        int col = n0 + wn + j * 16 + mfrag;
        Cc[(size_t)row * N + col] = acc[i][j][rr];
      }
}

// ---------------- bf16x3 split-precision MFMA GEMM, B^T, split-K partials --------
__global__ __launch_bounds__(256, 3) void gemm_bt3_p(const u16* __restrict__ Ah,
                                                     const u16* __restrict__ Al,
                                                     const u16* __restrict__ Bh,
                                                     const u16* __restrict__ Bl,
                                                     float* __restrict__ C,
                                                     int lda, int ldb, int ldc,
                                                     int K, int KC, size_t chunkStride,
                                                     int causal) {
  int bm = gridDim.x - 1 - blockIdx.x, bn = blockIdx.y, kc = blockIdx.z;
  if (causal && bn > bm) return;
  int kStart = kc * KC;
  if (kStart >= K) return;
  int kStop = kStart + KC < K ? kStart + KC : K;
  __shared__ __align__(16) u16 Ash[128 * 32];
  __shared__ __align__(16) u16 Asl[128 * 32];
  __shared__ __align__(16) u16 Bsh[128 * 32];
  __shared__ __align__(16) u16 Bsl[128 * 32];
  int t = threadIdx.x;
  int lane = t & 63, w = t >> 6;
  int m0 = bm * 128, n0 = bn * 128;
  int wm = (w >> 1) * 64, wn = (w & 1) * 64;
  int mfrag = lane & 15, quad = lane >> 4;
  int srow = t >> 2, schunk = t & 3;
  float* Cc = C + (size_t)kc * chunkStride;
  f32x4 acc[4][4] = {};
  for (int kt = kStart; kt < kStop; kt += 32) {
#pragma unroll
    for (int p = 0; p < 2; ++p) {
      int row = p * 64 + srow;
      size_t aoff = (size_t)(m0 + row) * lda + kt + schunk * 8;
      size_t boff = (size_t)(n0 + row) * ldb + kt + schunk * 8;
      size_t loff = (size_t)(p * 256 + t) * 8;
      gl_lds16(Ah + aoff, Ash + loff);
      gl_lds16(Al + aoff, Asl + loff);
      gl_lds16(Bh + boff, Bsh + loff);
      gl_lds16(Bl + boff, Bsl + loff);
    }
    __syncthreads();
    s16x8 a0[4], a1[4], b0[4];
#pragma unroll
    for (int i = 0; i < 4; ++i)
      a0[i] = *(const s16x8*)(Ash + (wm + i * 16 + mfrag) * 32 + quad * 8);
#pragma unroll
    for (int j = 0; j < 4; ++j)
      b0[j] = *(const s16x8*)(Bsh + (wn + j * 16 + mfrag) * 32 + quad * 8);
#pragma unroll
    for (int i = 0; i < 4; ++i)
#pragma unroll
      for (int j = 0; j < 4; ++j)
        acc[i][j] = __builtin_amdgcn_mfma_f32_16x16x32_bf16(a0[i], b0[j], acc[i][j], 0, 0, 0);
#pragma unroll
    for (int i = 0; i < 4; ++i)
      a1[i] = *(const s16x8*)(Asl + (wm + i * 16 + mfrag) * 32 + quad * 8);
#pragma unroll
    for (int i = 0; i < 4; ++i)
#pragma unroll
      for (int j = 0; j < 4; ++j)
        acc[i][j] = __builtin_amdgcn_mfma_f32_16x16x32_bf16(a1[i], b0[j], acc[i][j], 0, 0, 0);
#pragma unroll
    for (int j = 0; j < 4; ++j)
      b0[j] = *(const s16x8*)(Bsl + (wn + j * 16 + mfrag) * 32 + quad * 8);
#pragma unroll
    for (int i = 0; i < 4; ++i)
#pragma unroll
      for (int j = 0; j < 4; ++j)
        acc[i][j] = __builtin_amdgcn_mfma_f32_16x16x32_bf16(a0[i], b0[j], acc[i][j], 0, 0, 0);
    __syncthreads();
  }
#pragma unroll
  for (int i = 0; i < 4; ++i)
#pragma unroll
    for (int j = 0; j < 4; ++j)
#pragma unroll
      for (int rr = 0; rr < 4; ++rr) {
        int row = m0 + wm + i * 16 + quad * 4 + rr;
        int col = n0 + wn + j * 16 + mfrag;
        Cc[(size_t)row * ldc + col] = acc[i][j][rr];
      }
}

extern "C" void kernel_launch(void* const* d_in, const int* in_sizes, int n_in,
                              void* d_out, int out_size, void* d_ws, size_t ws_size,
                              hipStream_t stream) {
  const float* x  = (const float*)d_in[0];
  const float* Wk = (const float*)d_in[1];
  const float* Wq = (const float*)d_in[2];
  const float* W2 = (const float*)d_in[3];

  char* ws = (char*)d_ws;
  const size_t MB = 1024 * 1024;
  // persistent region [0, 78 MB)
  u16*   QKh  = (u16*)  (ws + 0);            //  2 MB  [4096,256] hi
  u16*   QKl  = (u16*)  (ws + 2 * MB);       //  2 MB  lo
  u16*   Wh   = (u16*)  (ws + 4 * MB);       //  1 MB  [256,2048] (Wq ; Wk) hi
  u16*   Wl   = (u16*)  (ws + 5 * MB);       //  1 MB  lo
  u16*   xT   = (u16*)  (ws + 6 * MB);       // 16 MB  [2048,4096] bf16
  u16*   W2b  = (u16*)  (ws + 22 * MB);      //  8 MB  [2048,2048] bf16
  u16*   outb = (u16*)  (ws + 30 * MB);      // 16 MB  [4096,2048] bf16
  u16*   attn = (u16*)  (ws + 46 * MB);      // 32 MB  [4096,4096] bf16
  // reusable region A [78, 142 MB) — lifetimes strictly sequential:
  u16*   xh   = (u16*)  (ws + 78 * MB);      // 16 MB  (dead after qk gemm)
  u16*   xl   = (u16*)  (ws + 94 * MB);      // 16 MB  (dead after qk gemm)
  float* QKp  = (float*)(ws + 110 * MB);     // 32 MB  8 x [4096,256] partials
  float* S    = (float*)(ws + 78 * MB);      // 64 MB  scores (after xh/xl/QKp dead)
  float* P0   = (float*)(ws + 78 * MB);      // 32 MB  partial chunk 0 (after S dead)
  float* P1   = (float*)(ws + 110 * MB);     // 32 MB  partial chunk 1

  const int XN4 = NCTX * DMODEL / 4;
  const int QKN4 = NCTX * 256 / 4;

  // fused prep: x split + Wq/Wk splits + W2 cast + transpose  (14848 blocks)
  prep_all<<<14848, 256, 0, stream>>>(x, Wq, Wk, W2, xh, xl, Wh, Wl, W2b, xT);

  // q,k = x @ [Wq;Wk]^T via bf16x3, split-K KC=256 -> 512 blocks, 8 partials
  gemm_bt3_p<<<dim3(NCTX / 128, 2, 8), 256, 0, stream>>>(
      xh, xl, Wh, Wl, QKp, DMODEL, DMODEL, 256, DMODEL, 256, (size_t)NCTX * 256, 0);
  reduce8_split<<<(QKN4 + 255) / 256, 256, 0, stream>>>(QKp, QKh, QKl, QKN4);

  // scores = q @ k^T (lower-triangular tiles), K=128: single chunk, direct store
  gemm_bt3_p<<<dim3(NCTX / 128, NCTX / 128, 1), 256, 0, stream>>>(
      QKh, QKl, QKh + DHEAD, QKl + DHEAD, S, 256, 256, NCTX, DHEAD, DHEAD, 0, 1);
  softmax_rows<<<NCTX, 256, 0, stream>>>(S, attn);

  // out = attn @ x (causal), split-K KC=2048 -> 768 active blocks, 2 partials
  gemm_bt_p<<<dim3(NCTX / 128, DMODEL / 128, 2), 256, 0, stream>>>(
      attn, xT, P0, NCTX, DMODEL, NCTX, 2048, 1);
  reduce2_cast<<<(XN4 + 255) / 256, 256, 0, stream>>>(P0, P1, outb, XN4,
                                                      2048 * 2048 / 4);

  // final = out @ W2^T, split-K KC=1024 -> 1024 blocks, 2 partials
  gemm_bt_p<<<dim3(NCTX / 128, DMODEL / 128, 2), 256, 0, stream>>>(
      outb, W2b, P0, NCTX, DMODEL, DMODEL, 1024, 0);
  reduce2_f32<<<(XN4 + 255) / 256, 256, 0, stream>>>(P0, P1, (float*)d_out, XN4);
}